// Round 11
// baseline (13571.104 us; speedup 1.0000x reference)
//
#include <hip/hip_runtime.h>
#include <hip/hip_bf16.h>

#define HH 64
#define TT 512
#define BB 16

typedef __attribute__((ext_vector_type(8))) short short8;
typedef __attribute__((ext_vector_type(4))) float f32x4;
typedef __attribute__((ext_vector_type(2))) float f32x2;

#define K1 1.4426950408889634f   // log2(e)   — sigmoid-type pre-scale
#define K2 2.8853900817779268f   // 2*log2(e) — tanh-type pre-scale

static __device__ __forceinline__ unsigned short f2bf(float f) {
  unsigned u = __float_as_uint(f);
  u += 0x7fffu + ((u >> 16) & 1u);   // RNE (one-time weight pack only)
  return (unsigned short)(u >> 16);
}

static __device__ __forceinline__ short8 pack8s(const float* __restrict__ p, float s) {
  short8 r;
  #pragma unroll
  for (int i = 0; i < 8; ++i) r[i] = (short)f2bf(p[i] * s);
  return r;
}

static __device__ __forceinline__ f32x2 splat2(float b) { f32x2 r; r[0] = b; r[1] = b; return r; }
static __device__ __forceinline__ f32x2 vexp2(f32x2 v) {
  f32x2 r; r[0] = __builtin_amdgcn_exp2f(v[0]); r[1] = __builtin_amdgcn_exp2f(v[1]); return r;
}
static __device__ __forceinline__ f32x2 vrcp(f32x2 v) {
  f32x2 r; r[0] = __builtin_amdgcn_rcpf(v[0]); r[1] = __builtin_amdgcn_rcpf(v[1]); return r;
}
static __device__ __forceinline__ f32x2 vmin2(f32x2 a, float b) {
  return __builtin_elementwise_min(a, splat2(b));
}

// 7-trans LSTM cell update for a PAIR of hidden units (validated R6-R10).
static __device__ __forceinline__ f32x2 lstm_act2(f32x2 zi, f32x2 zf, f32x2 zg,
                                                  f32x2 zo, f32x2& c) {
  f32x2 Ei = vexp2(vmin2(zi, 16.f));
  f32x2 Ef = vexp2(vmin2(zf, 16.f));
  f32x2 G  = vexp2(vmin2(zg, 23.f));
  f32x2 Eo = vexp2(vmin2(zo, 16.f));
  f32x2 Pi = Ei + 1.f, Pf = Ef + 1.f, Pg = G + 1.f, Gm = G - 1.f;
  f32x2 t2 = Pi * Pg;
  f32x2 N  = Ef * c * t2 + Ei * Gm * Pf;
  f32x2 D  = Pf * t2;
  c = N * vrcp(D);
  f32x2 C2 = vexp2(vmin2(c * K2, 23.f));
  f32x2 num = Eo * (C2 - 1.f);
  f32x2 den = (Eo + 1.f) * (C2 + 1.f);
  return num * vrcp(den);
}

#define MF(A, B, C) __builtin_amdgcn_mfma_f32_16x16x32_bf16((A), (B), (C), 0, 0, 0)

#define AGENT __HIP_MEMORY_SCOPE_AGENT

// ======================= split producer/consumer kernel =======================
// Grid 512: bid<256 = A-WG (layer 0) for batch group bid; else B-WG (layer 1+FC)
// for group bid-256. A streams h0(t) through a 4-slot ring in d_ws (device-scope
// 8B atomics); per-A-wave release flags aprog[g][w]; B publishes bprog[g].
__global__ __launch_bounds__(256, 2)
void lstm2_split(const float* __restrict__ x,
                 const float* __restrict__ Wih0, const float* __restrict__ Whh0,
                 const float* __restrict__ bih0, const float* __restrict__ bhh0,
                 const float* __restrict__ Wih1, const float* __restrict__ Whh1,
                 const float* __restrict__ bih1, const float* __restrict__ bhh1,
                 const float* __restrict__ Wfc,  const float* __restrict__ bfc,
                 float* __restrict__ out,
                 unsigned long long* __restrict__ ring64,   // [256][4][256] u64
                 unsigned* __restrict__ aprog,              // [256][4]
                 unsigned* __restrict__ bprog)              // [256]
{
  __shared__ float xs[TT * BB];                              // A only (32 KB)
  __shared__ __align__(16) unsigned short hbuf[2][BB * HH];  // A: h0 dbuf / B: h1 dbuf
  __shared__ float h1f[BB * HH];                             // B only

  const int tid  = threadIdx.x;
  const int w    = tid >> 6;       // wave 0..3 = column-block
  const int lane = tid & 63;
  const int m    = lane & 15;
  const int q    = lane >> 4;
  const int g    = blockIdx.x & 255;
  const int g4   = g * 4;
  const bool isA = (blockIdx.x < 256);

  // zero h dbuf (2048 ushorts = 1024 uints)
  ((unsigned int*)hbuf)[tid]       = 0; ((unsigned int*)hbuf)[tid + 256] = 0;
  ((unsigned int*)hbuf)[tid + 512] = 0; ((unsigned int*)hbuf)[tid + 768] = 0;

  // loop-invariant LDS byte offsets (swizzle: 16B blocks XOR (row&7)<<4)
  const int colw = 16 * w + m;
  const int rdo0 = m * 128 + ((q * 16) ^ ((m & 7) << 4));
  const int rdo1 = m * 128 + ((64 + q * 16) ^ ((m & 7) << 4));
  int wro[4];
  #pragma unroll
  for (int j = 0; j < 4; ++j) {
    const int row = q * 4 + j;
    wro[j] = row * 128 + ((2 * colw) ^ ((row & 7) << 4));
  }

  if (isA) {
    // ---------------- producer: layer 0 ----------------
    for (int t = tid; t < TT; t += 256) {
      #pragma unroll
      for (int r = 0; r < BB; ++r)
        xs[t * BB + r] = x[(size_t)(g * BB + r) * TT + t];
    }
    short8 wf[8];
    f32x4 bs[4];
    f32x2 wxs[4];
    #pragma unroll
    for (int n = 0; n < 4; ++n) {
      const float s = (n == 2) ? K2 : K1;
      const int colg = 16 * (4 * n + w) + m;
      const float b = (bih0[colg] + bhh0[colg]) * s;
      bs[n][0] = b; bs[n][1] = b; bs[n][2] = b; bs[n][3] = b;
      wxs[n] = splat2(Wih0[colg] * s);
      #pragma unroll
      for (int kt = 0; kt < 2; ++kt)
        wf[n * 2 + kt] = pack8s(Whh0 + colg * HH + kt * 32 + q * 8, s);
    }
    // copy-out addressing: wave w copies its own 16-col block, lane -> 8B chunk
    const int crow = lane >> 2, cc = lane & 3;
    const int lco  = crow * 128 + ((32 * w + cc * 8) ^ ((crow & 7) << 4));  // LDS byte
    const int gco  = crow * 16 + 4 * w + cc;                                // u64 idx in tile
    unsigned cB = 0;   // cached bprog

    __syncthreads();

    f32x2 cst01 = splat2(0.f), cst23 = splat2(0.f);
    const float* xpf = xs + q * 4;

#define SA_BODY(P, T) {                                                        \
    if (lane == 0)                                                             \
      __hip_atomic_store(&aprog[g4 + w], (unsigned)(T), __ATOMIC_RELEASE, AGENT); \
    if ((int)cB < (T) - 3) {                                                   \
      while ((int)(cB = __hip_atomic_load(&bprog[g], __ATOMIC_RELAXED, AGENT)) \
             < (T) - 3) __builtin_amdgcn_s_sleep(2);                           \
    }                                                                          \
    const char* rd = (const char*)hbuf[(P) ^ 1];                               \
    short8 af0 = *(const short8*)(rd + rdo0);                                  \
    short8 af1 = *(const short8*)(rd + rdo1);                                  \
    f32x4 xv = *(const f32x4*)xpf; xpf += BB;                                  \
    f32x4 a0 = MF(af0, wf[0], bs[0]); a0 = MF(af1, wf[1], a0);                 \
    f32x4 a1 = MF(af0, wf[2], bs[1]); a1 = MF(af1, wf[3], a1);                 \
    f32x4 a2 = MF(af0, wf[4], bs[2]); a2 = MF(af1, wf[5], a2);                 \
    f32x4 a3 = MF(af0, wf[6], bs[3]); a3 = MF(af1, wf[7], a3);                 \
    char* wrb = (char*)hbuf[P];                                                \
    {                                                                          \
      f32x2 xp2 = {xv[0], xv[1]};                                              \
      f32x2 zi = {a0[0], a0[1]}; zi += xp2 * wxs[0];                           \
      f32x2 zf = {a1[0], a1[1]}; zf += xp2 * wxs[1];                           \
      f32x2 zg = {a2[0], a2[1]}; zg += xp2 * wxs[2];                           \
      f32x2 zo = {a3[0], a3[1]}; zo += xp2 * wxs[3];                           \
      f32x2 h2 = lstm_act2(zi, zf, zg, zo, cst01);                             \
      *(__hip_bfloat16*)(wrb + wro[0]) = __float2bfloat16(h2[0]);              \
      *(__hip_bfloat16*)(wrb + wro[1]) = __float2bfloat16(h2[1]);              \
    }                                                                          \
    {                                                                          \
      f32x2 xp2 = {xv[2], xv[3]};                                              \
      f32x2 zi = {a0[2], a0[3]}; zi += xp2 * wxs[0];                           \
      f32x2 zf = {a1[2], a1[3]}; zf += xp2 * wxs[1];                           \
      f32x2 zg = {a2[2], a2[3]}; zg += xp2 * wxs[2];                           \
      f32x2 zo = {a3[2], a3[3]}; zo += xp2 * wxs[3];                           \
      f32x2 h2 = lstm_act2(zi, zf, zg, zo, cst23);                             \
      *(__hip_bfloat16*)(wrb + wro[2]) = __float2bfloat16(h2[0]);              \
      *(__hip_bfloat16*)(wrb + wro[3]) = __float2bfloat16(h2[1]);              \
    }                                                                          \
    unsigned long long cv = *(const unsigned long long*)((char*)hbuf[P] + lco);\
    __hip_atomic_store(&ring64[(size_t)(g4 + ((T) & 3)) * 256 + gco], cv,      \
                       __ATOMIC_RELAXED, AGENT);                               \
    __syncthreads();                                                           \
  }

    #pragma unroll 1
    for (int k = 0; k < TT / 2; ++k) {
      SA_BODY(0, 2 * k)
      SA_BODY(1, 2 * k + 1)
    }
    if (lane == 0)
      __hip_atomic_store(&aprog[g4 + w], (unsigned)TT, __ATOMIC_RELEASE, AGENT);
  } else {
    // ---------------- consumer: layer 1 + FC ----------------
    short8 wf[16];
    f32x4 bs[4];
    #pragma unroll
    for (int n = 0; n < 4; ++n) {
      const float s = (n == 2) ? K2 : K1;
      const int colg = 16 * (4 * n + w) + m;
      const float b = (bih1[colg] + bhh1[colg]) * s;
      bs[n][0] = b; bs[n][1] = b; bs[n][2] = b; bs[n][3] = b;
      #pragma unroll
      for (int kt = 0; kt < 4; ++kt) {   // kt 0,1: Wih1 (h0 input); kt 2,3: Whh1
        const float* Wsrc = (kt < 2) ? Wih1 : Whh1;
        wf[n * 4 + kt] = pack8s(Wsrc + colg * HH + (kt & 1) * 32 + q * 8, s);
      }
    }
    // global h0 fragment u64 indices within a 2KB tile (linear [16][64] bf16)
    const int i0 = m * 16 + q * 2, i1 = i0 + 1;
    const int i2 = i0 + 8,         i3 = i2 + 1;
    unsigned cA = 0;   // cached min(aprog[g][0..3])

#define CONF_A(V) if ((int)cA < (V)) {                                         \
    for (;;) {                                                                 \
      unsigned m0 = __hip_atomic_load(&aprog[g4 + 0], __ATOMIC_ACQUIRE, AGENT);\
      unsigned m1 = __hip_atomic_load(&aprog[g4 + 1], __ATOMIC_ACQUIRE, AGENT);\
      unsigned m2 = __hip_atomic_load(&aprog[g4 + 2], __ATOMIC_ACQUIRE, AGENT);\
      unsigned m3 = __hip_atomic_load(&aprog[g4 + 3], __ATOMIC_ACQUIRE, AGENT);\
      unsigned mn = m0 < m1 ? m0 : m1;                                         \
      mn = mn < m2 ? mn : m2; mn = mn < m3 ? mn : m3;                          \
      cA = mn;                                                                 \
      if ((int)cA >= (V)) break;                                               \
      __builtin_amdgcn_s_sleep(2);                                             \
    } }

    __syncthreads();

    f32x2 cst01 = splat2(0.f), cst23 = splat2(0.f);
    // prime prefetch for tau=0
    CONF_A(1)
    unsigned long long d0, d1, d2, d3;
    {
      const size_t b64 = (size_t)g4 * 256;
      d0 = __hip_atomic_load(&ring64[b64 + i0], __ATOMIC_RELAXED, AGENT);
      d1 = __hip_atomic_load(&ring64[b64 + i1], __ATOMIC_RELAXED, AGENT);
      d2 = __hip_atomic_load(&ring64[b64 + i2], __ATOMIC_RELAXED, AGENT);
      d3 = __hip_atomic_load(&ring64[b64 + i3], __ATOMIC_RELAXED, AGENT);
    }

#define SB_BODY(P, T) {                                                        \
    if (tid == 0)                                                              \
      __hip_atomic_store(&bprog[g], (unsigned)(T), __ATOMIC_RELAXED, AGENT);   \
    short8 af0, af1;                                                           \
    { unsigned long long dd[2];                                                \
      dd[0] = d0; dd[1] = d1; __builtin_memcpy(&af0, dd, 16);                  \
      dd[0] = d2; dd[1] = d3; __builtin_memcpy(&af1, dd, 16); }                \
    const char* rd1 = (const char*)hbuf[(P) ^ 1];                              \
    short8 af2 = *(const short8*)(rd1 + rdo0);                                 \
    short8 af3 = *(const short8*)(rd1 + rdo1);                                 \
    f32x4 a0 = MF(af0, wf[0],  bs[0]); a0 = MF(af1, wf[1],  a0);               \
    a0 = MF(af2, wf[2],  a0);  a0 = MF(af3, wf[3],  a0);                       \
    f32x4 a1 = MF(af0, wf[4],  bs[1]); a1 = MF(af1, wf[5],  a1);               \
    a1 = MF(af2, wf[6],  a1);  a1 = MF(af3, wf[7],  a1);                       \
    f32x4 a2 = MF(af0, wf[8],  bs[2]); a2 = MF(af1, wf[9],  a2);               \
    a2 = MF(af2, wf[10], a2);  a2 = MF(af3, wf[11], a2);                       \
    f32x4 a3 = MF(af0, wf[12], bs[3]); a3 = MF(af1, wf[13], a3);               \
    a3 = MF(af2, wf[14], a3);  a3 = MF(af3, wf[15], a3);                       \
    if ((T) + 1 < TT) {                                                        \
      CONF_A((T) + 2)                                                          \
      const size_t b64 = (size_t)(g4 + (((T) + 1) & 3)) * 256;                 \
      d0 = __hip_atomic_load(&ring64[b64 + i0], __ATOMIC_RELAXED, AGENT);      \
      d1 = __hip_atomic_load(&ring64[b64 + i1], __ATOMIC_RELAXED, AGENT);      \
      d2 = __hip_atomic_load(&ring64[b64 + i2], __ATOMIC_RELAXED, AGENT);      \
      d3 = __hip_atomic_load(&ring64[b64 + i3], __ATOMIC_RELAXED, AGENT);      \
    }                                                                          \
    char* wrb = (char*)hbuf[P];                                                \
    const bool last = ((T) == TT - 1);                                         \
    {                                                                          \
      f32x2 zi = {a0[0], a0[1]}, zf = {a1[0], a1[1]};                          \
      f32x2 zg = {a2[0], a2[1]}, zo = {a3[0], a3[1]};                          \
      f32x2 h2 = lstm_act2(zi, zf, zg, zo, cst01);                             \
      *(__hip_bfloat16*)(wrb + wro[0]) = __float2bfloat16(h2[0]);              \
      *(__hip_bfloat16*)(wrb + wro[1]) = __float2bfloat16(h2[1]);              \
      if (last) {                                                              \
        h1f[(q * 4 + 0) * HH + colw] = h2[0];                                  \
        h1f[(q * 4 + 1) * HH + colw] = h2[1];                                  \
      }                                                                        \
    }                                                                          \
    {                                                                          \
      f32x2 zi = {a0[2], a0[3]}, zf = {a1[2], a1[3]};                          \
      f32x2 zg = {a2[2], a2[3]}, zo = {a3[2], a3[3]};                          \
      f32x2 h2 = lstm_act2(zi, zf, zg, zo, cst23);                             \
      *(__hip_bfloat16*)(wrb + wro[2]) = __float2bfloat16(h2[0]);              \
      *(__hip_bfloat16*)(wrb + wro[3]) = __float2bfloat16(h2[1]);              \
      if (last) {                                                              \
        h1f[(q * 4 + 2) * HH + colw] = h2[0];                                  \
        h1f[(q * 4 + 3) * HH + colw] = h2[1];                                  \
      }                                                                        \
    }                                                                          \
    __syncthreads();                                                           \
  }

    #pragma unroll 1
    for (int k = 0; k < TT / 2; ++k) {
      SB_BODY(0, 2 * k)
      SB_BODY(1, 2 * k + 1)
    }

    // FC epilogue
    if (tid < BB * 7) {
      const int b = tid / 7, o = tid % 7;
      float s = bfc[o];
      #pragma unroll
      for (int kk = 0; kk < HH; ++kk) s = fmaf(h1f[b * HH + kk], Wfc[o * HH + kk], s);
      out[(size_t)(g * BB + b) * 7 + o] = s;
    }
  }
}

// ======================= fallback: R7 single-WG kernel (369 us) ==============
#define STEP_A(P) {                                                            \
    const char* rd = (const char*)h0buf[(P) ^ 1];                              \
    short8 af0 = *(const short8*)(rd + rdo0);                                  \
    short8 af1 = *(const short8*)(rd + rdo1);                                  \
    f32x4 xv = *(const f32x4*)xpf; xpf += BB;                                  \
    f32x4 a0 = MF(af0, wf[0], bs[0]); a0 = MF(af1, wf[1], a0);                 \
    f32x4 a1 = MF(af0, wf[2], bs[1]); a1 = MF(af1, wf[3], a1);                 \
    f32x4 a2 = MF(af0, wf[4], bs[2]); a2 = MF(af1, wf[5], a2);                 \
    f32x4 a3 = MF(af0, wf[6], bs[3]); a3 = MF(af1, wf[7], a3);                 \
    char* wrb = (char*)h0buf[P];                                               \
    {                                                                          \
      f32x2 xp2 = {xv[0], xv[1]};                                              \
      f32x2 zi = {a0[0], a0[1]}; zi += xp2 * wxs[0];                           \
      f32x2 zf = {a1[0], a1[1]}; zf += xp2 * wxs[1];                           \
      f32x2 zg = {a2[0], a2[1]}; zg += xp2 * wxs[2];                           \
      f32x2 zo = {a3[0], a3[1]}; zo += xp2 * wxs[3];                           \
      f32x2 h2 = lstm_act2(zi, zf, zg, zo, cst01);                             \
      *(__hip_bfloat16*)(wrb + wro[0]) = __float2bfloat16(h2[0]);              \
      *(__hip_bfloat16*)(wrb + wro[1]) = __float2bfloat16(h2[1]);              \
    }                                                                          \
    {                                                                          \
      f32x2 xp2 = {xv[2], xv[3]};                                              \
      f32x2 zi = {a0[2], a0[3]}; zi += xp2 * wxs[0];                           \
      f32x2 zf = {a1[2], a1[3]}; zf += xp2 * wxs[1];                           \
      f32x2 zg = {a2[2], a2[3]}; zg += xp2 * wxs[2];                           \
      f32x2 zo = {a3[2], a3[3]}; zo += xp2 * wxs[3];                           \
      f32x2 h2 = lstm_act2(zi, zf, zg, zo, cst23);                             \
      *(__hip_bfloat16*)(wrb + wro[2]) = __float2bfloat16(h2[0]);              \
      *(__hip_bfloat16*)(wrb + wro[3]) = __float2bfloat16(h2[1]);              \
    }                                                                          \
  }

#define STEP_B(P, LAST) {                                                      \
    const char* rd0 = (const char*)h0buf[(P) ^ 1];                             \
    const char* rd1 = (const char*)h1buf[P];                                   \
    short8 af0 = *(const short8*)(rd0 + rdo0);                                 \
    short8 af1 = *(const short8*)(rd0 + rdo1);                                 \
    short8 af2 = *(const short8*)(rd1 + rdo0);                                 \
    short8 af3 = *(const short8*)(rd1 + rdo1);                                 \
    f32x4 a0 = MF(af0, wf[0],  bs[0]); a0 = MF(af1, wf[1],  a0);               \
    a0 = MF(af2, wf[2],  a0);  a0 = MF(af3, wf[3],  a0);                       \
    f32x4 a1 = MF(af0, wf[4],  bs[1]); a1 = MF(af1, wf[5],  a1);               \
    a1 = MF(af2, wf[6],  a1);  a1 = MF(af3, wf[7],  a1);                       \
    f32x4 a2 = MF(af0, wf[8],  bs[2]); a2 = MF(af1, wf[9],  a2);               \
    a2 = MF(af2, wf[10], a2);  a2 = MF(af3, wf[11], a2);                       \
    f32x4 a3 = MF(af0, wf[12], bs[3]); a3 = MF(af1, wf[13], a3);               \
    a3 = MF(af2, wf[14], a3);  a3 = MF(af3, wf[15], a3);                       \
    char* wrb = (char*)h1buf[(P) ^ 1];                                         \
    {                                                                          \
      f32x2 zi = {a0[0], a0[1]}, zf = {a1[0], a1[1]};                          \
      f32x2 zg = {a2[0], a2[1]}, zo = {a3[0], a3[1]};                          \
      f32x2 h2 = lstm_act2(zi, zf, zg, zo, cst01);                             \
      *(__hip_bfloat16*)(wrb + wro[0]) = __float2bfloat16(h2[0]);              \
      *(__hip_bfloat16*)(wrb + wro[1]) = __float2bfloat16(h2[1]);              \
      if (LAST) {                                                              \
        h1f[(q * 4 + 0) * HH + colw] = h2[0];                                  \
        h1f[(q * 4 + 1) * HH + colw] = h2[1];                                  \
      }                                                                        \
    }                                                                          \
    {                                                                          \
      f32x2 zi = {a0[2], a0[3]}, zf = {a1[2], a1[3]};                          \
      f32x2 zg = {a2[2], a2[3]}, zo = {a3[2], a3[3]};                          \
      f32x2 h2 = lstm_act2(zi, zf, zg, zo, cst23);                             \
      *(__hip_bfloat16*)(wrb + wro[2]) = __float2bfloat16(h2[0]);              \
      *(__hip_bfloat16*)(wrb + wro[3]) = __float2bfloat16(h2[1]);              \
      if (LAST) {                                                              \
        h1f[(q * 4 + 2) * HH + colw] = h2[0];                                  \
        h1f[(q * 4 + 3) * HH + colw] = h2[1];                                  \
      }                                                                        \
    }                                                                          \
  }

__global__ __launch_bounds__(512, 2)
void lstm2_fused(const float* __restrict__ x,
                 const float* __restrict__ Wih0, const float* __restrict__ Whh0,
                 const float* __restrict__ bih0, const float* __restrict__ bhh0,
                 const float* __restrict__ Wih1, const float* __restrict__ Whh1,
                 const float* __restrict__ bih1, const float* __restrict__ bhh1,
                 const float* __restrict__ Wfc,  const float* __restrict__ bfc,
                 float* __restrict__ out)
{
  __shared__ float xs[TT * BB];
  __shared__ __align__(16) unsigned short h0buf[2][BB * HH];
  __shared__ __align__(16) unsigned short h1buf[2][BB * HH];
  __shared__ float h1f[BB * HH];

  const int tid  = threadIdx.x;
  const int wave = tid >> 6;
  const int lane = tid & 63;
  const int grp  = wave >> 2;
  const int w    = wave & 3;
  const int m    = lane & 15;
  const int q    = lane >> 4;
  const int b0   = blockIdx.x * BB;

  {
    const int t = tid;
    #pragma unroll
    for (int r = 0; r < BB; ++r)
      xs[t * BB + r] = x[(size_t)(b0 + r) * TT + t];
  }
  ((unsigned int*)h0buf)[tid] = 0; ((unsigned int*)h0buf)[tid + 512] = 0;
  ((unsigned int*)h1buf)[tid] = 0; ((unsigned int*)h1buf)[tid + 512] = 0;

  short8 wf[16];
  f32x4 bs[4];
  f32x2 wxs[4];
  #pragma unroll
  for (int n = 0; n < 4; ++n) {
    const float s = (n == 2) ? K2 : K1;
    const int colg = 16 * (4 * n + w) + m;
    if (grp == 0) {
      const float b = (bih0[colg] + bhh0[colg]) * s;
      bs[n][0] = b; bs[n][1] = b; bs[n][2] = b; bs[n][3] = b;
      wxs[n] = splat2(Wih0[colg] * s);
      #pragma unroll
      for (int kt = 0; kt < 2; ++kt)
        wf[n * 2 + kt] = pack8s(Whh0 + colg * HH + kt * 32 + q * 8, s);
    } else {
      const float b = (bih1[colg] + bhh1[colg]) * s;
      bs[n][0] = b; bs[n][1] = b; bs[n][2] = b; bs[n][3] = b;
      wxs[n] = splat2(0.f);
      #pragma unroll
      for (int kt = 0; kt < 4; ++kt) {
        const float* Wsrc = (kt < 2) ? Wih1 : Whh1;
        wf[n * 4 + kt] = pack8s(Wsrc + colg * HH + (kt & 1) * 32 + q * 8, s);
      }
    }
  }

  const int colw = 16 * w + m;
  const int rdo0 = m * 128 + ((q * 16) ^ ((m & 7) << 4));
  const int rdo1 = m * 128 + ((64 + q * 16) ^ ((m & 7) << 4));
  int wro[4];
  #pragma unroll
  for (int j = 0; j < 4; ++j) {
    const int row = q * 4 + j;
    wro[j] = row * 128 + ((2 * colw) ^ ((row & 7) << 4));
  }

  __syncthreads();

  f32x2 cst01 = splat2(0.f), cst23 = splat2(0.f);
  const float* xpf = xs + q * 4;

  if (grp == 0) { STEP_A(0) }
  __syncthreads();

  #pragma unroll 1
  for (int k = 0; k < (TT - 2) / 2; ++k) {
    if (grp == 0) { STEP_A(1) } else { STEP_B(1, false) }
    __syncthreads();
    if (grp == 0) { STEP_A(0) } else { STEP_B(0, false) }
    __syncthreads();
  }
  if (grp == 0) { STEP_A(1) } else { STEP_B(1, false) }
  __syncthreads();
  if (grp == 1) { STEP_B(0, true) }
  __syncthreads();

  if (tid < BB * 7) {
    const int b = tid / 7, o = tid % 7;
    float s = bfc[o];
    #pragma unroll
    for (int k = 0; k < HH; ++k) s = fmaf(h1f[b * HH + k], Wfc[o * HH + k], s);
    out[(size_t)(b0 + b) * 7 + o] = s;
  }
}

extern "C" void kernel_launch(void* const* d_in, const int* in_sizes, int n_in,
                              void* d_out, int out_size, void* d_ws, size_t ws_size,
                              hipStream_t stream) {
  const float* x    = (const float*)d_in[0];
  const float* Wih0 = (const float*)d_in[1];
  const float* Whh0 = (const float*)d_in[2];
  const float* bih0 = (const float*)d_in[3];
  const float* bhh0 = (const float*)d_in[4];
  const float* Wih1 = (const float*)d_in[5];
  const float* Whh1 = (const float*)d_in[6];
  const float* bih1 = (const float*)d_in[7];
  const float* bhh1 = (const float*)d_in[8];
  const float* Wfc  = (const float*)d_in[9];
  const float* bfc  = (const float*)d_in[10];
  float* out = (float*)d_out;

  const size_t RING_B   = (size_t)256 * 4 * 2048;   // 2 MB: [256 groups][4 slots][2KB tile]
  const size_t APROG_O  = RING_B;                   // [256][4] u32 = 4 KB
  const size_t BPROG_O  = RING_B + 4096;            // [256]    u32 = 1 KB
  const size_t NEED     = RING_B + 4096 + 1024;

  if (ws_size >= NEED) {
    // zero the flag region every call (harness does not re-poison between replays)
    hipMemsetAsync((char*)d_ws + APROG_O, 0, 5120, stream);
    dim3 grid(512);   // 256 A-WGs (layer 0) + 256 B-WGs (layer 1 + FC)
    dim3 block(256);
    hipLaunchKernelGGL(lstm2_split, grid, block, 0, stream,
                       x, Wih0, Whh0, bih0, bhh0, Wih1, Whh1, bih1, bhh1, Wfc, bfc, out,
                       (unsigned long long*)d_ws,
                       (unsigned*)((char*)d_ws + APROG_O),
                       (unsigned*)((char*)d_ws + BPROG_O));
  } else {
    dim3 grid(4096 / BB);
    dim3 block(512);
    hipLaunchKernelGGL(lstm2_fused, grid, block, 0, stream,
                       x, Wih0, Whh0, bih0, bhh0, Wih1, Whh1, bih1, bhh1, Wfc, bfc, out);
  }
}

// Round 12
// 368.803 us; speedup vs baseline: 36.7977x; 36.7977x over previous
//
#include <hip/hip_runtime.h>
#include <hip/hip_bf16.h>

#define HH 64
#define TT 512
#define BB 16

typedef __attribute__((ext_vector_type(8))) short short8;
typedef __attribute__((ext_vector_type(4))) float f32x4;
typedef __attribute__((ext_vector_type(2))) float f32x2;

#define K1 1.4426950408889634f   // log2(e)   — sigmoid-type pre-scale
#define K2 2.8853900817779268f   // 2*log2(e) — tanh-type pre-scale

static __device__ __forceinline__ unsigned short f2bf(float f) {
  unsigned u = __float_as_uint(f);
  u += 0x7fffu + ((u >> 16) & 1u);   // RNE (one-time weight pack only)
  return (unsigned short)(u >> 16);
}

static __device__ __forceinline__ short8 pack8s(const float* __restrict__ p, float s) {
  short8 r;
  #pragma unroll
  for (int i = 0; i < 8; ++i) r[i] = (short)f2bf(p[i] * s);
  return r;
}

static __device__ __forceinline__ f32x2 splat2(float b) { f32x2 r; r[0] = b; r[1] = b; return r; }
static __device__ __forceinline__ f32x2 vexp2(f32x2 v) {
  f32x2 r; r[0] = __builtin_amdgcn_exp2f(v[0]); r[1] = __builtin_amdgcn_exp2f(v[1]); return r;
}
static __device__ __forceinline__ f32x2 vrcp(f32x2 v) {
  f32x2 r; r[0] = __builtin_amdgcn_rcpf(v[0]); r[1] = __builtin_amdgcn_rcpf(v[1]); return r;
}
static __device__ __forceinline__ f32x2 vmin2(f32x2 a, float b) {
  return __builtin_elementwise_min(a, splat2(b));
}

// 7-trans LSTM cell update for a PAIR of hidden units (validated R6-R10:
// absmax identical to the 10-trans reference form).
// zi,zf,zo pre-scaled by K1; zg pre-scaled by K2; c in natural units.
// sigmoid(z)=E/(1+E) with E=e^z;  tanh(z)=(G-1)/(G+1) with G=e^{2z}.
static __device__ __forceinline__ f32x2 lstm_act2(f32x2 zi, f32x2 zf, f32x2 zg,
                                                  f32x2 zo, f32x2& c) {
  f32x2 Ei = vexp2(vmin2(zi, 16.f));       // upper clamp only: exp2(-big)->0 safe
  f32x2 Ef = vexp2(vmin2(zf, 16.f));
  f32x2 G  = vexp2(vmin2(zg, 23.f));
  f32x2 Eo = vexp2(vmin2(zo, 16.f));
  f32x2 Pi = Ei + 1.f, Pf = Ef + 1.f, Pg = G + 1.f, Gm = G - 1.f;
  f32x2 t2 = Pi * Pg;
  f32x2 N  = Ef * c * t2 + Ei * Gm * Pf;
  f32x2 D  = Pf * t2;
  c = N * vrcp(D);                          // c' = f*c + i*g  (exact mod fp32)
  f32x2 C2 = vexp2(vmin2(c * K2, 23.f));
  f32x2 num = Eo * (C2 - 1.f);
  f32x2 den = (Eo + 1.f) * (C2 + 1.f);
  return num * vrcp(den);                   // h = o * tanh(c')
}

#define MF(A, B, C) __builtin_amdgcn_mfma_f32_16x16x32_bf16((A), (B), (C), 0, 0, 0)

// ---- one LSTM-layer-0 step, phase P (compile-time). Reads h0buf[P^1], writes h0buf[P].
#define STEP_A(P) {                                                            \
    const char* rd = (const char*)h0buf[(P) ^ 1];                              \
    short8 af0 = *(const short8*)(rd + rdo0);                                  \
    short8 af1 = *(const short8*)(rd + rdo1);                                  \
    f32x4 xv = *(const f32x4*)xpf; xpf += BB;                                  \
    f32x4 a0 = MF(af0, wf[0], bs[0]); a0 = MF(af1, wf[1], a0);                 \
    f32x4 a1 = MF(af0, wf[2], bs[1]); a1 = MF(af1, wf[3], a1);                 \
    f32x4 a2 = MF(af0, wf[4], bs[2]); a2 = MF(af1, wf[5], a2);                 \
    f32x4 a3 = MF(af0, wf[6], bs[3]); a3 = MF(af1, wf[7], a3);                 \
    char* wrb = (char*)h0buf[P];                                               \
    {                                                                          \
      f32x2 xp2 = {xv[0], xv[1]};                                              \
      f32x2 zi = {a0[0], a0[1]}; zi += xp2 * wxs[0];                           \
      f32x2 zf = {a1[0], a1[1]}; zf += xp2 * wxs[1];                           \
      f32x2 zg = {a2[0], a2[1]}; zg += xp2 * wxs[2];                           \
      f32x2 zo = {a3[0], a3[1]}; zo += xp2 * wxs[3];                           \
      f32x2 h2 = lstm_act2(zi, zf, zg, zo, cst01);                             \
      *(__hip_bfloat16*)(wrb + wro[0]) = __float2bfloat16(h2[0]);              \
      *(__hip_bfloat16*)(wrb + wro[1]) = __float2bfloat16(h2[1]);              \
    }                                                                          \
    {                                                                          \
      f32x2 xp2 = {xv[2], xv[3]};                                              \
      f32x2 zi = {a0[2], a0[3]}; zi += xp2 * wxs[0];                           \
      f32x2 zf = {a1[2], a1[3]}; zf += xp2 * wxs[1];                           \
      f32x2 zg = {a2[2], a2[3]}; zg += xp2 * wxs[2];                           \
      f32x2 zo = {a3[2], a3[3]}; zo += xp2 * wxs[3];                           \
      f32x2 h2 = lstm_act2(zi, zf, zg, zo, cst23);                             \
      *(__hip_bfloat16*)(wrb + wro[2]) = __float2bfloat16(h2[0]);              \
      *(__hip_bfloat16*)(wrb + wro[3]) = __float2bfloat16(h2[1]);              \
    }                                                                          \
  }

// ---- one LSTM-layer-1 step, phase P. Reads h0buf[P^1] (input) + h1buf[P]
// (recurrent, 2 steps old), writes h1buf[P^1].
#define STEP_B(P, LAST) {                                                      \
    const char* rd0 = (const char*)h0buf[(P) ^ 1];                             \
    const char* rd1 = (const char*)h1buf[P];                                   \
    short8 af0 = *(const short8*)(rd0 + rdo0);                                 \
    short8 af1 = *(const short8*)(rd0 + rdo1);                                 \
    short8 af2 = *(const short8*)(rd1 + rdo0);                                 \
    short8 af3 = *(const short8*)(rd1 + rdo1);                                 \
    f32x4 a0 = MF(af0, wf[0],  bs[0]); a0 = MF(af1, wf[1],  a0);               \
    a0 = MF(af2, wf[2],  a0);  a0 = MF(af3, wf[3],  a0);                       \
    f32x4 a1 = MF(af0, wf[4],  bs[1]); a1 = MF(af1, wf[5],  a1);               \
    a1 = MF(af2, wf[6],  a1);  a1 = MF(af3, wf[7],  a1);                       \
    f32x4 a2 = MF(af0, wf[8],  bs[2]); a2 = MF(af1, wf[9],  a2);               \
    a2 = MF(af2, wf[10], a2);  a2 = MF(af3, wf[11], a2);                       \
    f32x4 a3 = MF(af0, wf[12], bs[3]); a3 = MF(af1, wf[13], a3);               \
    a3 = MF(af2, wf[14], a3);  a3 = MF(af3, wf[15], a3);                       \
    char* wrb = (char*)h1buf[(P) ^ 1];                                         \
    {                                                                          \
      f32x2 zi = {a0[0], a0[1]}, zf = {a1[0], a1[1]};                          \
      f32x2 zg = {a2[0], a2[1]}, zo = {a3[0], a3[1]};                          \
      f32x2 h2 = lstm_act2(zi, zf, zg, zo, cst01);                             \
      *(__hip_bfloat16*)(wrb + wro[0]) = __float2bfloat16(h2[0]);              \
      *(__hip_bfloat16*)(wrb + wro[1]) = __float2bfloat16(h2[1]);              \
      if (LAST) {                                                              \
        h1f[(q * 4 + 0) * HH + colw] = h2[0];                                  \
        h1f[(q * 4 + 1) * HH + colw] = h2[1];                                  \
      }                                                                        \
    }                                                                          \
    {                                                                          \
      f32x2 zi = {a0[2], a0[3]}, zf = {a1[2], a1[3]};                          \
      f32x2 zg = {a2[2], a2[3]}, zo = {a3[2], a3[3]};                          \
      f32x2 h2 = lstm_act2(zi, zf, zg, zo, cst23);                             \
      *(__hip_bfloat16*)(wrb + wro[2]) = __float2bfloat16(h2[0]);              \
      *(__hip_bfloat16*)(wrb + wro[3]) = __float2bfloat16(h2[1]);              \
      if (LAST) {                                                              \
        h1f[(q * 4 + 2) * HH + colw] = h2[0];                                  \
        h1f[(q * 4 + 3) * HH + colw] = h2[1];                                  \
      }                                                                        \
    }                                                                          \
  }

__global__ __launch_bounds__(512, 2)
void lstm2_fused(const float* __restrict__ x,
                 const float* __restrict__ Wih0, const float* __restrict__ Whh0,
                 const float* __restrict__ bih0, const float* __restrict__ bhh0,
                 const float* __restrict__ Wih1, const float* __restrict__ Whh1,
                 const float* __restrict__ bih1, const float* __restrict__ bhh1,
                 const float* __restrict__ Wfc,  const float* __restrict__ bfc,
                 float* __restrict__ out)
{
  __shared__ float xs[TT * BB];                               // 32 KB, xs[t][row]
  __shared__ __align__(16) unsigned short h0buf[2][BB * HH];  // dbuf bf16, swizzled
  __shared__ __align__(16) unsigned short h1buf[2][BB * HH];
  __shared__ float h1f[BB * HH];                              // fp32 final h1

  const int tid  = threadIdx.x;
  const int wave = tid >> 6;
  const int lane = tid & 63;
  const int grp  = wave >> 2;      // 0: layer0 (4 waves), 1: layer1 (4 waves)
  const int w    = wave & 3;       // column-block 0..3
  const int m    = lane & 15;
  const int q    = lane >> 4;
  const int b0   = blockIdx.x * BB;

  // ---- stage x transposed: xs[t][r] = x[b0+r][t] ----
  {
    const int t = tid;             // blockDim.x == 512 == TT
    #pragma unroll
    for (int r = 0; r < BB; ++r)
      xs[t * BB + r] = x[(size_t)(b0 + r) * TT + t];
  }
  // zero h state (bf16 zero == 0x0000): each buf = 1024 uints
  ((unsigned int*)h0buf)[tid] = 0; ((unsigned int*)h0buf)[tid + 512] = 0;
  ((unsigned int*)h1buf)[tid] = 0; ((unsigned int*)h1buf)[tid + 512] = 0;

  // ---- pack PRE-SCALED weight B-fragments (held in VGPRs the whole loop) ----
  // wave w owns gate n-tiles {4n+w}: n=0->i,1->f,2->g,3->o, cols 16w..16w+15.
  // Scale K1 for i,f,o; K2 for g -> MFMA emits log2-domain pre-activations.
  short8 wf[16];
  f32x4 bs[4];
  f32x2 wxs[4];
  #pragma unroll
  for (int n = 0; n < 4; ++n) {
    const float s = (n == 2) ? K2 : K1;
    const int colg = 16 * (4 * n + w) + m;
    if (grp == 0) {
      const float b = (bih0[colg] + bhh0[colg]) * s;
      bs[n][0] = b; bs[n][1] = b; bs[n][2] = b; bs[n][3] = b;
      wxs[n] = splat2(Wih0[colg] * s);
      #pragma unroll
      for (int kt = 0; kt < 2; ++kt)
        wf[n * 2 + kt] = pack8s(Whh0 + colg * HH + kt * 32 + q * 8, s);
    } else {
      const float b = (bih1[colg] + bhh1[colg]) * s;
      bs[n][0] = b; bs[n][1] = b; bs[n][2] = b; bs[n][3] = b;
      wxs[n] = splat2(0.f);
      #pragma unroll
      for (int kt = 0; kt < 4; ++kt) {   // kt 0,1: Wih1 (h0 input); kt 2,3: Whh1
        const float* Wsrc = (kt < 2) ? Wih1 : Whh1;
        wf[n * 4 + kt] = pack8s(Wsrc + colg * HH + (kt & 1) * 32 + q * 8, s);
      }
    }
  }

  // ---- loop-invariant LDS byte offsets (swizzle: 16B blocks XOR (row&7)<<4) ----
  const int colw = 16 * w + m;     // my h column within [0,64)
  const int rdo0 = m * 128 + ((q * 16) ^ ((m & 7) << 4));        // kt=0 A-frag
  const int rdo1 = m * 128 + ((64 + q * 16) ^ ((m & 7) << 4));   // kt=1 A-frag
  int wro[4];
  #pragma unroll
  for (int j = 0; j < 4; ++j) {
    const int row = q * 4 + j;
    wro[j] = row * 128 + ((2 * colw) ^ ((row & 7) << 4));
  }

  __syncthreads();   // x staged + h zeroed

  f32x2 cst01 = splat2(0.f), cst23 = splat2(0.f);
  const float* xpf = xs + q * 4;   // advances 16 floats per layer-0 step

  // Iteration t (phase P = t&1): A computes L0 step t (t<TT);
  // B computes L1 step t-1 (t>=1). ONE barrier per step.
  if (grp == 0) { STEP_A(0) }      // t=0 peel
  __syncthreads();

  #pragma unroll 1
  for (int k = 0; k < (TT - 2) / 2; ++k) {   // t = 1..510
    if (grp == 0) { STEP_A(1) } else { STEP_B(1, false) }
    __syncthreads();
    if (grp == 0) { STEP_A(0) } else { STEP_B(0, false) }
    __syncthreads();
  }
  // t=511 (P=1): both.
  if (grp == 0) { STEP_A(1) } else { STEP_B(1, false) }
  __syncthreads();
  // t=512 (P=0): B only, final h1 spilled to fp32.
  if (grp == 1) { STEP_B(0, true) }
  __syncthreads();

  // ---- FC epilogue: out[b][o] = h1_final[b] . Wfc[o] + bfc[o] ----
  if (tid < BB * 7) {
    const int b = tid / 7, o = tid % 7;
    float s = bfc[o];
    #pragma unroll
    for (int k = 0; k < HH; ++k) s = fmaf(h1f[b * HH + k], Wfc[o * HH + k], s);
    out[(size_t)(b0 + b) * 7 + o] = s;
  }
}

extern "C" void kernel_launch(void* const* d_in, const int* in_sizes, int n_in,
                              void* d_out, int out_size, void* d_ws, size_t ws_size,
                              hipStream_t stream) {
  const float* x    = (const float*)d_in[0];
  const float* Wih0 = (const float*)d_in[1];
  const float* Whh0 = (const float*)d_in[2];
  const float* bih0 = (const float*)d_in[3];
  const float* bhh0 = (const float*)d_in[4];
  const float* Wih1 = (const float*)d_in[5];
  const float* Whh1 = (const float*)d_in[6];
  const float* bih1 = (const float*)d_in[7];
  const float* bhh1 = (const float*)d_in[8];
  const float* Wfc  = (const float*)d_in[9];
  const float* bfc  = (const float*)d_in[10];
  float* out = (float*)d_out;

  dim3 grid(4096 / BB);   // 256 workgroups, 1 per CU
  dim3 block(512);        // 8 waves: 4 layer-0 + 4 layer-1, pipelined
  hipLaunchKernelGGL(lstm2_fused, grid, block, 0, stream,
                     x, Wih0, Whh0, bih0, bhh0, Wih1, Whh1, bih1, bhh1, Wfc, bfc, out);
}